// Round 22
// baseline (102.486 us; speedup 1.0000x reference)
//
#include <hip/hip_runtime.h>
#include <hip/hip_bf16.h>
#include <cstdint>
#include <math.h>

// Problem constants
#define B_DIM 2
#define T_SEQ 2048
#define C_DIM 1024
#define H_NUM 16
#define D_HEAD 64
#define M_ROWS (B_DIM * T_SEQ)      // 4096
#define N_QKV (3 * H_NUM * D_HEAD)  // 3072

using short8  = __attribute__((ext_vector_type(8))) short;
using short4v = __attribute__((ext_vector_type(4))) short;
using f32x4   = __attribute__((ext_vector_type(4))) float;

__device__ __forceinline__ short f2bf(float f) {
  union { __hip_bfloat16 h; short s; } u;
  u.h = __float2bfloat16(f);
  return u.s;
}
__device__ __forceinline__ float bf2f(short s) {
  union { unsigned u; float f; } v;
  v.u = ((unsigned)(unsigned short)s) << 16;
  return v.f;
}

// pack hi16(a),hi16(b) -> one u32 (truncating f32->bf16 pair; safe for p>=0)
__device__ __forceinline__ unsigned pk2bf(float a, float b) {
  union { float f; unsigned u; } ua, ub;
  ua.f = a; ub.f = b;
  return __builtin_amdgcn_perm(ub.u, ua.u, 0x07060302u);
}

// async global->LDS, 16B per lane (m97 pattern: per-lane LDS ptr = base + lane*16B)
__device__ __forceinline__ void gld_lds16(short* lds, const short* g) {
  __builtin_amdgcn_global_load_lds(
      (const unsigned int __attribute__((address_space(1)))*)g,
      (unsigned int __attribute__((address_space(3)))*)lds, 16, 0, 0);
}

// counted-vmcnt barrier cluster (T4): loads stay in flight across the barrier.
#define BAR_VM(N)                                                    \
  do {                                                               \
    asm volatile("s_waitcnt vmcnt(" #N ") lgkmcnt(0)" ::: "memory"); \
    __builtin_amdgcn_s_barrier();                                    \
    __builtin_amdgcn_sched_barrier(0);                               \
  } while (0)

// ---------------------------------------------------------------------------
// Fused prologue kernel: one dispatch replaces {cvt x, cvt Wo, pack_w}.
// ---------------------------------------------------------------------------
__global__ __launch_bounds__(256) void prep(const float* __restrict__ x,
                                            const float* __restrict__ Wo,
                                            const float* __restrict__ Wq,
                                            const float* __restrict__ Wk,
                                            const float* __restrict__ Wv,
                                            short* __restrict__ xb,
                                            short* __restrict__ Wob,
                                            short* __restrict__ Wt) {
  int bid = blockIdx.x;
  int tid = threadIdx.x;
  if (bid < 2560) {
    const float* in = (bid < 2048) ? x : Wo;
    short* out      = (bid < 2048) ? xb : Wob;
    int i = ((bid < 2048) ? bid : (bid - 2048)) * 256 + tid;
    const float4* p = reinterpret_cast<const float4*>(in) + (size_t)i * 2;
    float4 a = p[0], b = p[1];
    short8 o;
    o[0] = f2bf(a.x); o[1] = f2bf(a.y); o[2] = f2bf(a.z); o[3] = f2bf(a.w);
    o[4] = f2bf(b.x); o[5] = f2bf(b.y); o[6] = f2bf(b.z); o[7] = f2bf(b.w);
    reinterpret_cast<short8*>(out)[i] = o;
    return;
  }
  int pid  = bid - 2560;
  int proj = pid >> 8;
  int h    = (pid >> 4) & 15;
  int cb   = pid & 15;
  const float* W = (proj == 0) ? Wq : ((proj == 1) ? Wk : Wv);
  const float* src = W + ((size_t)h * C_DIM + (size_t)cb * 64) * D_HEAD;

  __shared__ float tile[64][65];
#pragma unroll
  for (int j = 0; j < 4; j++) {
    int flat = tid + j * 256;
    int c    = flat >> 4;
    int d4   = flat & 15;
    float4 v = reinterpret_cast<const float4*>(src + (size_t)c * D_HEAD)[d4];
    tile[c][d4 * 4 + 0] = v.x;
    tile[c][d4 * 4 + 1] = v.y;
    tile[c][d4 * 4 + 2] = v.z;
    tile[c][d4 * 4 + 3] = v.w;
  }
  __syncthreads();

  int d     = tid >> 2;
  int cpart = (tid & 3) * 16;
  short* dst = Wt + ((size_t)(proj * H_NUM + h) * D_HEAD + d) * C_DIM + cb * 64 + cpart;
  short8 o0, o1;
#pragma unroll
  for (int j = 0; j < 8; j++) {
    o0[j] = f2bf(tile[cpart + j][d]);
    o1[j] = f2bf(tile[cpart + 8 + j][d]);
  }
  *reinterpret_cast<short8*>(dst)     = o0;
  *reinterpret_cast<short8*>(dst + 8) = o1;
}

// ---------------------------------------------------------------------------
// GEMM: C[M,N] = A[M,K] @ Bt[N,K]^T, bf16 in, f32 accum. (r19 structure —
// best measured: BMTx128 tile, BK=32, linear LDS + chunk-XOR fragment swizzle,
// global_load_lds w=16, 3-deep staging + counted vmcnt, XCD-chunked swizzle,
// no setprio. MODE 0: LDS-coalesced scatter epilogue. MODE 1: bias + f32.
// ---------------------------------------------------------------------------
template <int MODE, int BMT>
__global__ __launch_bounds__(256) void gemm_bt(
    const short* __restrict__ A, const short* __restrict__ Bt,
    const float* __restrict__ bias,
    short* __restrict__ qb, short* __restrict__ kb, short* __restrict__ vtb,
    float* __restrict__ outb,
    int M, int N, int K) {
  constexpr int BK = 32;
  constexpr int MR = BMT / 32;
  constexpr int NLA = BMT / 64;
  __shared__ short GL[3 * (BMT + 128) * BK];
  short* Asb = GL;
  short* Bsb = GL + 3 * BMT * BK;

  int tid  = threadIdx.x;
  int lane = tid & 63;
  int wv   = tid >> 6;
  int q15  = lane & 15, g = lane >> 4;
  int ntn  = N >> 7;
  int bpx  = (M / BMT) >> 3;
  int xcd  = blockIdx.x & 7;
  int idx  = blockIdx.x >> 3;
  int bn   = idx / bpx;
  int bm   = xcd * bpx + (idx - bn * bpx);
  int row0 = bm * BMT, col0 = bn << 7;
  int wm   = (wv >> 1) * (BMT / 2);
  int wn   = (wv & 1) << 6;

  f32x4 acc[MR][4];
#pragma unroll
  for (int i = 0; i < MR; i++)
#pragma unroll
    for (int j = 0; j < 4; j++) acc[i][j] = (f32x4){0.f, 0.f, 0.f, 0.f};

  int srccol = ((tid & 3) ^ ((tid >> 3) & 3)) * 8;
  const short* ag = A  + (size_t)(row0 + (tid >> 2)) * K + srccol;
  const short* bg = Bt + (size_t)(col0 + (tid >> 2)) * K + srccol;
  const size_t gstep = (size_t)64 * K;

  auto stage = [&](int ks, int buf) {
    const short* a  = ag + (size_t)ks * BK;
    const short* bb = bg + (size_t)ks * BK;
    gld_lds16(Asb + buf * BMT * BK + tid * 8, a);
    if constexpr (NLA == 2)
      gld_lds16(Asb + buf * BMT * BK + 64 * BK + tid * 8, a + gstep);
    gld_lds16(Bsb + buf * 128 * BK + tid * 8, bb);
    gld_lds16(Bsb + buf * 128 * BK + 64 * BK + tid * 8, bb + gstep);
  };

  int nk = K / BK;
  stage(0, 0);
  stage(1, 1);
  if constexpr (NLA == 2) {
    asm volatile("s_waitcnt vmcnt(4)" ::: "memory");
  } else {
    asm volatile("s_waitcnt vmcnt(3)" ::: "memory");
  }
  __builtin_amdgcn_s_barrier();
  __builtin_amdgcn_sched_barrier(0);

  int rpos = (g ^ ((q15 >> 1) & 3)) * 8;

  for (int k = 0; k < nk; ++k) {
    int buf = k % 3;
    if (k + 2 < nk) stage(k + 2, (k + 2) % 3);

    short8 af[MR], bf[4];
#pragma unroll
    for (int mi = 0; mi < MR; mi++)
      af[mi] = *reinterpret_cast<const short8*>(
          &Asb[buf * BMT * BK + (wm + mi * 16 + q15) * BK + rpos]);
#pragma unroll
    for (int ni = 0; ni < 4; ni++)
      bf[ni] = *reinterpret_cast<const short8*>(
          &Bsb[buf * 128 * BK + (wn + ni * 16 + q15) * BK + rpos]);
#pragma unroll
    for (int mi = 0; mi < MR; mi++)
#pragma unroll
      for (int ni = 0; ni < 4; ni++)
        acc[mi][ni] = __builtin_amdgcn_mfma_f32_16x16x32_bf16(af[mi], bf[ni],
                                                              acc[mi][ni], 0, 0, 0);

    if (k + 1 < nk) {
      if (k + 2 < nk) {
        if constexpr (NLA == 2) { BAR_VM(4); } else { BAR_VM(3); }
      } else {
        BAR_VM(0);
      }
    }
  }

  // ---------------- epilogue ----------------
  if constexpr (MODE == 0) {
    constexpr int LDT = 136;
    int proj  = col0 >> 10;
    int b     = row0 >> 11;
    int trow0 = row0 & (T_SEQ - 1);
    int h0    = (col0 >> 6) & 15;
    __syncthreads();
    if (proj < 2) {
      float scl = (proj == 0) ? 0.125f * 1.44269504f : 1.0f;  // log2-domain q
#pragma unroll
      for (int mi = 0; mi < MR; mi++)
#pragma unroll
        for (int ni = 0; ni < 4; ni++) {
          int t0 = wm + mi * 16 + (g << 2);
          int d2 = wn + ni * 16 + q15;
#pragma unroll
          for (int r = 0; r < 4; r++)
            GL[(t0 + r) * LDT + d2] = f2bf(acc[mi][ni][r] * scl);
        }
      __syncthreads();
      short* dstb = (proj == 0) ? qb : kb;
#pragma unroll
      for (int ps = 0; ps < 8; ps++) {
        int trow  = ps * 16 + (tid >> 4);
        int chunk = tid & 15;
        int hh    = h0 + (chunk >> 3);
        int d     = (chunk & 7) * 8;
        short8 v = *reinterpret_cast<const short8*>(&GL[trow * LDT + chunk * 8]);
        *reinterpret_cast<short8*>(
            dstb + ((size_t)(b * H_NUM + hh) * T_SEQ + trow0 + trow) * D_HEAD + d) = v;
      }
    } else {
#pragma unroll
      for (int mi = 0; mi < MR; mi++)
#pragma unroll
        for (int ni = 0; ni < 4; ni++) {
          int t0 = wm + mi * 16 + (g << 2);
          int d2 = wn + ni * 16 + q15;
          short4v pk;
#pragma unroll
          for (int r = 0; r < 4; r++) pk[r] = f2bf(acc[mi][ni][r]);
          *reinterpret_cast<short4v*>(&GL[d2 * LDT + t0]) = pk;
        }
      __syncthreads();
#pragma unroll
      for (int ps = 0; ps < 8; ps++) {
        int drow  = ps * 16 + (tid >> 4);
        int chunk = tid & 15;
        int hh    = h0 + (drow >> 6);
        int d     = drow & 63;
        short8 v = *reinterpret_cast<const short8*>(&GL[drow * LDT + chunk * 8]);
        *reinterpret_cast<short8*>(
            vtb + ((size_t)(b * H_NUM + hh) * D_HEAD + d) * T_SEQ + trow0 +
            chunk * 8) = v;
      }
    }
  } else {
#pragma unroll
    for (int mi = 0; mi < MR; mi++) {
#pragma unroll
      for (int ni = 0; ni < 4; ni++) {
        int rb  = row0 + wm + mi * 16 + (g << 2);
        int col = col0 + wn + ni * 16 + q15;
        f32x4 v = acc[mi][ni];
        float bb = bias[col];
#pragma unroll
        for (int r = 0; r < 4; r++)
          outb[(size_t)(rb + r) * N + col] = v[r] + bb;
      }
    }
  }
}

// ---------------------------------------------------------------------------
// Flash attention v12: split-KV. Strips 0..20 run as single blocks (chunks
// 0..strip). Strips 21..31 split into TWO blocks by chunk range ([0,16) and
// [16,strip+1)) with independent online-softmax state; partial (undivided
// bf16 O + per-row m,l) goes into the dead Wt region; combine kernel merges.
// Critical path drops 32 -> 21 chunks; total staged chunks UNCHANGED (the
// split partitions the sweep — unlike r14's padding). Slot order is
// work-descending. Rest = r19 machinery (swapped S^T, LDS 2-buf K/V,
// 4 heads/XCD, log2-domain softmax, ones-MFMA row-sum, no setprio).
// ---------------------------------------------------------------------------
__global__ __launch_bounds__(256, 4) void attn_fwd(const short* __restrict__ qg,
                                                   const short* __restrict__ kg,
                                                   const short* __restrict__ vt,
                                                   short* __restrict__ ob,
                                                   short* __restrict__ Pp,
                                                   float* __restrict__ mlp) {
  int bid  = blockIdx.x;
  int bh   = (bid & 7) * 4 + ((bid >> 3) & 3);  // 4 heads per XCD
  int slot = bid >> 5;                           // 0..42, work-descending
  int strip, c0, c1, half = 0;
  bool part;
  if (slot < 5)       { strip = 20 - slot;  c0 = 0;  c1 = strip + 1; part = false; }
  else if (slot < 16) { strip = slot + 16;  c0 = 0;  c1 = 16;        part = true;  half = 0; }
  else if (slot < 27) { strip = 47 - slot;  c0 = 16; c1 = strip + 1; part = true;  half = 1; }
  else                { strip = 42 - slot;  c0 = 0;  c1 = strip + 1; part = false; }
  int b    = bh >> 4;
  int h    = bh & 15;
  int tid  = threadIdx.x, lane = tid & 63, wv = tid >> 6;
  int q15  = lane & 15, g = lane >> 4;
  int qr   = strip * 64 + wv * 16;      // wave's 16 q rows

  __shared__ short arena[16384];

  const short* qp = qg + (size_t)bh * T_SEQ * D_HEAD;
  const short* kp = kg + (size_t)bh * T_SEQ * D_HEAD;
  const short* vp = vt + (size_t)bh * D_HEAD * T_SEQ;

  int r8    = lane >> 3;
  int gcb   = ((lane & 7) * 16) ^ (r8 << 4);
  int srow0 = wv * 16;

  int hh = (q15 & 7) << 4;
  int koff0 = ((0 * 64 + g * 16) ^ hh) >> 1;
  int koff1 = ((1 * 64 + g * 16) ^ hh) >> 1;
  int voff[4];
#pragma unroll
  for (int st = 0; st < 4; st++) voff[st] = ((st * 32 + g * 8) ^ hh) >> 1;

  short8 qf[2];
#pragma unroll
  for (int kk = 0; kk < 2; kk++)
    qf[kk] = *reinterpret_cast<const short8*>(
        qp + (size_t)(qr + q15) * D_HEAD + kk * 32 + g * 8);

  f32x4 acc[4];
#pragma unroll
  for (int dt = 0; dt < 4; dt++) acc[dt] = (f32x4){0.f, 0.f, 0.f, 0.f};
  f32x4 lacc = (f32x4){0.f, 0.f, 0.f, 0.f};
  float m_ = -1e30f;

  const short4v ones4 = (short4v){(short)0x3F80, (short)0x3F80,
                                  (short)0x3F80, (short)0x3F80};

  auto stage = [&](int c, int pbuf) {
    const short* ks = kp + (size_t)(c * 64 + srow0 + r8) * D_HEAD + (gcb >> 1);
    const short* vs = vp + (size_t)(srow0 + r8) * T_SEQ + c * 64 + (gcb >> 1);
    short* kd = arena + pbuf * 4096 + srow0 * 64 + lane * 8;
    short* vd = arena + 8192 + pbuf * 4096 + srow0 * 64 + lane * 8;
    gld_lds16(kd, ks);
    gld_lds16(kd + 8 * 64, ks + (size_t)8 * D_HEAD);
    gld_lds16(vd, vs);
    gld_lds16(vd + 8 * 64, vs + (size_t)8 * T_SEQ);
  };

  stage(c0, c0 & 1);
  BAR_VM(0);

  for (int c = c0; c < c1; ++c) {
    int s0 = c * 64;
    if (c + 1 < c1) stage(c + 1, (c + 1) & 1);
    const short* Kb = arena + (c & 1) * 4096;
    const short* Vb = arena + 8192 + (c & 1) * 4096;

    short8 kf[4][2];
#pragma unroll
    for (int st = 0; st < 4; st++) {
      int rbase = (st * 16 + q15) * 64;
      kf[st][0] = *reinterpret_cast<const short8*>(&Kb[rbase + koff0]);
      kf[st][1] = *reinterpret_cast<const short8*>(&Kb[rbase + koff1]);
    }

    f32x4 sv[4];
#pragma unroll
    for (int st = 0; st < 4; st++) {
      f32x4 s = (f32x4){0.f, 0.f, 0.f, 0.f};
      s = __builtin_amdgcn_mfma_f32_16x16x32_bf16(kf[st][0], qf[0], s, 0, 0, 0);
      s = __builtin_amdgcn_mfma_f32_16x16x32_bf16(kf[st][1], qf[1], s, 0, 0, 0);
      sv[st] = s;
    }

    short4v vf[4][4];
#pragma unroll
    for (int st = 0; st < 4; st++)
#pragma unroll
      for (int dt = 0; dt < 4; dt++)
        vf[st][dt] = *reinterpret_cast<const short4v*>(
            &Vb[(dt * 16 + q15) * 64 + voff[st]]);

    if (c == strip) {  // only the block whose range holds chunk==strip masks
#pragma unroll
      for (int st = 0; st < 4; st++)
#pragma unroll
        for (int r2 = 0; r2 < 4; r2++) {
          int sg = s0 + st * 16 + g * 4 + r2;
          if (sg > qr + q15) sv[st][r2] = -1e30f;
        }
    }

    float t0 = fmaxf(fmaxf(sv[0][0], sv[0][1]), sv[0][2]);
    float t1 = fmaxf(fmaxf(sv[0][3], sv[1][0]), sv[1][1]);
    float t2 = fmaxf(fmaxf(sv[1][2], sv[1][3]), sv[2][0]);
    float t3 = fmaxf(fmaxf(sv[2][1], sv[2][2]), sv[2][3]);
    float t4 = fmaxf(fmaxf(sv[3][0], sv[3][1]), sv[3][2]);
    float mx = fmaxf(fmaxf(fmaxf(t0, t1), t2),
                     fmaxf(fmaxf(t3, t4), sv[3][3]));
    mx = fmaxf(mx, __shfl_xor(mx, 16));
    mx = fmaxf(mx, __shfl_xor(mx, 32));

    if (!__all(mx <= m_ + 11.5f)) {
      float mnew = fmaxf(m_, mx);
      float sc   = __builtin_amdgcn_exp2f(m_ - mnew);
      m_ = mnew;
      lacc *= sc;
#pragma unroll
      for (int dt = 0; dt < 4; dt++) acc[dt] *= sc;
    }
    float mcur = m_;

    short4v pbf[4];
#pragma unroll
    for (int st = 0; st < 4; st++) {
      float p0 = __builtin_amdgcn_exp2f(sv[st][0] - mcur);
      float p1 = __builtin_amdgcn_exp2f(sv[st][1] - mcur);
      float p2 = __builtin_amdgcn_exp2f(sv[st][2] - mcur);
      float p3 = __builtin_amdgcn_exp2f(sv[st][3] - mcur);
      union { short4v s; unsigned u[2]; } P;
      P.u[0] = pk2bf(p0, p1);
      P.u[1] = pk2bf(p2, p3);
      pbf[st] = P.s;
    }

#pragma unroll
    for (int st = 0; st < 4; st++) {
#if __has_builtin(__builtin_amdgcn_mfma_f32_16x16x16bf16_1k)
      lacc = __builtin_amdgcn_mfma_f32_16x16x16bf16_1k(ones4, pbf[st], lacc, 0, 0, 0);
#pragma unroll
      for (int dt = 0; dt < 4; dt++)
        acc[dt] = __builtin_amdgcn_mfma_f32_16x16x16bf16_1k(
            vf[st][dt], pbf[st], acc[dt], 0, 0, 0);
#else
      short4v p4 = pbf[st];
      short8 bz = (short8){p4[0], p4[1], p4[2], p4[3], 0, 0, 0, 0};
      short8 oz = (short8){(short)0x3F80, (short)0x3F80, (short)0x3F80,
                           (short)0x3F80, 0, 0, 0, 0};
      lacc = __builtin_amdgcn_mfma_f32_16x16x32_bf16(oz, bz, lacc, 0, 0, 0);
#pragma unroll
      for (int dt = 0; dt < 4; dt++) {
        short4v v4 = vf[st][dt];
        short8 az = (short8){v4[0], v4[1], v4[2], v4[3], 0, 0, 0, 0};
        acc[dt] =
            __builtin_amdgcn_mfma_f32_16x16x32_bf16(az, bz, acc[dt], 0, 0, 0);
      }
#endif
    }

    BAR_VM(0);
  }

  // epilogue: per-wave transpose via arena (loop ended with barrier+lgkm0)
  short* OlW = arena + wv * (16 * 68);
  if (!part) {
    float inv = 1.0f / lacc[0];
#pragma unroll
    for (int dt = 0; dt < 4; dt++)
#pragma unroll
      for (int r2 = 0; r2 < 4; r2++)
        OlW[q15 * 68 + dt * 16 + g * 4 + r2] = f2bf(acc[dt][r2] * inv);
    int row = lane >> 2, cb = (lane & 3) * 16;
    size_t base = ((size_t)(b * T_SEQ) + qr + row) * C_DIM + h * 64 + cb;
    const short* src = OlW + row * 68 + cb;
    *reinterpret_cast<short8*>(ob + base) = *reinterpret_cast<const short8*>(src);
    *reinterpret_cast<short8*>(ob + base + 8) =
        *reinterpret_cast<const short8*>(src + 8);
  } else {
    // partial: undivided O (bf16) + per-row m,l
#pragma unroll
    for (int dt = 0; dt < 4; dt++)
#pragma unroll
      for (int r2 = 0; r2 < 4; r2++)
        OlW[q15 * 68 + dt * 16 + g * 4 + r2] = f2bf(acc[dt][r2]);
    int si = strip - 21;
    int row = lane >> 2, cb = (lane & 3) * 16;
    size_t pbase = ((size_t)(bh * 11 + si) * 2 + half) * 4096 +
                   (wv * 16 + row) * 64 + cb;
    const short* src = OlW + row * 68 + cb;
    *reinterpret_cast<short8*>(Pp + pbase) =
        *reinterpret_cast<const short8*>(src);
    *reinterpret_cast<short8*>(Pp + pbase + 8) =
        *reinterpret_cast<const short8*>(src + 8);
    if (lane < 16) {
      float* mlr = mlp + ((size_t)((bh * 11 + si) * 2 + half)) * 128 +
                   (wv * 16 + lane) * 2;
      mlr[0] = m_;
      mlr[1] = lacc[0];
    }
  }
}

// ---------------------------------------------------------------------------
// Combine kernel: merge the two partials of each split strip.
// grid = 32 bh * 11 strips = 352 blocks, 256 threads; thread t handles
// (row = t>>2, 16 d's at (t&3)*16).
// ---------------------------------------------------------------------------
__global__ __launch_bounds__(256) void combine(const short* __restrict__ Pp,
                                               const float* __restrict__ mlp,
                                               short* __restrict__ ob) {
  int bid = blockIdx.x;
  int bh  = bid / 11, si = bid % 11;
  int strip = si + 21;
  int b = bh >> 4, h = bh & 15;
  int t = threadIdx.x;
  int lr = t >> 2, dg = (t & 3) * 16;

  size_t mbase = ((size_t)(bh * 11 + si) * 2) * 128 + lr * 2;
  float m0 = mlp[mbase], l0 = mlp[mbase + 1];
  float m1 = mlp[mbase + 128], l1 = mlp[mbase + 129];
  float m  = fmaxf(m0, m1);
  float w0 = __builtin_amdgcn_exp2f(m0 - m);   // log2-domain m's
  float w1 = __builtin_amdgcn_exp2f(m1 - m);
  float inv = 1.0f / (l0 * w0 + l1 * w1);
  w0 *= inv;
  w1 *= inv;

  const short* P0 = Pp + ((size_t)(bh * 11 + si) * 2) * 4096 + lr * 64 + dg;
  const short* P1 = P0 + 4096;
  short8 a0 = *reinterpret_cast<const short8*>(P0);
  short8 a1 = *reinterpret_cast<const short8*>(P0 + 8);
  short8 c0 = *reinterpret_cast<const short8*>(P1);
  short8 c1 = *reinterpret_cast<const short8*>(P1 + 8);
  short8 o0, o1;
#pragma unroll
  for (int j = 0; j < 8; j++) {
    o0[j] = f2bf(bf2f(a0[j]) * w0 + bf2f(c0[j]) * w1);
    o1[j] = f2bf(bf2f(a1[j]) * w0 + bf2f(c1[j]) * w1);
  }
  short* dst = ob + ((size_t)(b * T_SEQ) + strip * 64 + lr) * C_DIM + h * 64 + dg;
  *reinterpret_cast<short8*>(dst)     = o0;
  *reinterpret_cast<short8*>(dst + 8) = o1;
}

// ---------------------------------------------------------------------------
// Launch. Workspace layout (needs >= 40 MB):
//   [0, 8M)        xb   bf16 x cast            (reused as obuf after QKV GEMM)
//   [8M, 14.3M)    Wt   bf16 packed QKV weights (DEAD after QKV GEMM ->
//                       reused as attn split partials: O 5.50MB + ml 0.36MB)
//   [14M, 16M)     Wob  bf16 Wo [1024][1024]
//   [16M, 24M)     qb   bf16 [B,H,T,D]  (prescaled by 0.125*log2e)
//   [24M, 32M)     kb   bf16 [B,H,T,D]
//   [32M, 40M)     vtb  bf16 [B,H,D,T]
// ---------------------------------------------------------------------------
extern "C" void kernel_launch(void* const* d_in, const int* in_sizes, int n_in,
                              void* d_out, int out_size, void* d_ws, size_t ws_size,
                              hipStream_t stream) {
  const float* x  = (const float*)d_in[0];
  const float* Wq = (const float*)d_in[1];
  const float* Wk = (const float*)d_in[2];
  const float* Wv = (const float*)d_in[3];
  const float* Wo = (const float*)d_in[4];
  const float* bo = (const float*)d_in[5];
  float* out = (float*)d_out;

  char* ws = (char*)d_ws;
  short* xb   = (short*)(ws + 0);
  short* Wt   = (short*)(ws + 8388608);
  short* Wob  = (short*)(ws + 14680064);
  short* qb   = (short*)(ws + 16777216);
  short* kb   = (short*)(ws + 25165824);
  short* vtb  = (short*)(ws + 33554432);
  short* obuf = xb;                         // reuse after QKV GEMM consumed xb
  short* Pp   = Wt;                         // reuse Wt after QKV GEMM: 5.50MB
  float* mlp  = (float*)(ws + 8388608 + 5767168);  // +0.36MB, total < 6.29MB

  prep<<<3328, 256, 0, stream>>>(x, Wo, Wq, Wk, Wv, xb, Wob, Wt);

  gemm_bt<0, 128><<<(M_ROWS / 128) * (N_QKV / 128), 256, 0, stream>>>(
      xb, Wt, nullptr, qb, kb, vtb, nullptr, M_ROWS, N_QKV, C_DIM);

  attn_fwd<<<1376, 256, 0, stream>>>(qb, kb, vtb, obuf, Pp, mlp);
  combine<<<352, 256, 0, stream>>>(Pp, mlp, obuf);

  gemm_bt<1, 64><<<(M_ROWS / 64) * (C_DIM / 128), 256, 0, stream>>>(
      obuf, Wob, bo, nullptr, nullptr, nullptr, out, M_ROWS, C_DIM, C_DIM);
}

// Round 23
// 101.459 us; speedup vs baseline: 1.0101x; 1.0101x over previous
//
#include <hip/hip_runtime.h>
#include <hip/hip_bf16.h>
#include <cstdint>
#include <math.h>

// Problem constants
#define B_DIM 2
#define T_SEQ 2048
#define C_DIM 1024
#define H_NUM 16
#define D_HEAD 64
#define M_ROWS (B_DIM * T_SEQ)      // 4096
#define N_QKV (3 * H_NUM * D_HEAD)  // 3072

using short8  = __attribute__((ext_vector_type(8))) short;
using short4v = __attribute__((ext_vector_type(4))) short;
using f32x4   = __attribute__((ext_vector_type(4))) float;

__device__ __forceinline__ short f2bf(float f) {
  union { __hip_bfloat16 h; short s; } u;
  u.h = __float2bfloat16(f);
  return u.s;
}

// pack hi16(a),hi16(b) -> one u32 (truncating f32->bf16 pair; safe for p>=0)
__device__ __forceinline__ unsigned pk2bf(float a, float b) {
  union { float f; unsigned u; } ua, ub;
  ua.f = a; ub.f = b;
  return __builtin_amdgcn_perm(ub.u, ua.u, 0x07060302u);
}

// async global->LDS, 16B per lane (m97 pattern: per-lane LDS ptr = base + lane*16B)
__device__ __forceinline__ void gld_lds16(short* lds, const short* g) {
  __builtin_amdgcn_global_load_lds(
      (const unsigned int __attribute__((address_space(1)))*)g,
      (unsigned int __attribute__((address_space(3)))*)lds, 16, 0, 0);
}

// counted-vmcnt barrier cluster (T4): loads stay in flight across the barrier.
#define BAR_VM(N)                                                    \
  do {                                                               \
    asm volatile("s_waitcnt vmcnt(" #N ") lgkmcnt(0)" ::: "memory"); \
    __builtin_amdgcn_s_barrier();                                    \
    __builtin_amdgcn_sched_barrier(0);                               \
  } while (0)

// ---------------------------------------------------------------------------
// Fused prologue kernel: one dispatch replaces {cvt x, cvt Wo, pack_w}.
// ---------------------------------------------------------------------------
__global__ __launch_bounds__(256) void prep(const float* __restrict__ x,
                                            const float* __restrict__ Wo,
                                            const float* __restrict__ Wq,
                                            const float* __restrict__ Wk,
                                            const float* __restrict__ Wv,
                                            short* __restrict__ xb,
                                            short* __restrict__ Wob,
                                            short* __restrict__ Wt) {
  int bid = blockIdx.x;
  int tid = threadIdx.x;
  if (bid < 2560) {
    const float* in = (bid < 2048) ? x : Wo;
    short* out      = (bid < 2048) ? xb : Wob;
    int i = ((bid < 2048) ? bid : (bid - 2048)) * 256 + tid;
    const float4* p = reinterpret_cast<const float4*>(in) + (size_t)i * 2;
    float4 a = p[0], b = p[1];
    short8 o;
    o[0] = f2bf(a.x); o[1] = f2bf(a.y); o[2] = f2bf(a.z); o[3] = f2bf(a.w);
    o[4] = f2bf(b.x); o[5] = f2bf(b.y); o[6] = f2bf(b.z); o[7] = f2bf(b.w);
    reinterpret_cast<short8*>(out)[i] = o;
    return;
  }
  int pid  = bid - 2560;
  int proj = pid >> 8;
  int h    = (pid >> 4) & 15;
  int cb   = pid & 15;
  const float* W = (proj == 0) ? Wq : ((proj == 1) ? Wk : Wv);
  const float* src = W + ((size_t)h * C_DIM + (size_t)cb * 64) * D_HEAD;

  __shared__ float tile[64][65];
#pragma unroll
  for (int j = 0; j < 4; j++) {
    int flat = tid + j * 256;
    int c    = flat >> 4;
    int d4   = flat & 15;
    float4 v = reinterpret_cast<const float4*>(src + (size_t)c * D_HEAD)[d4];
    tile[c][d4 * 4 + 0] = v.x;
    tile[c][d4 * 4 + 1] = v.y;
    tile[c][d4 * 4 + 2] = v.z;
    tile[c][d4 * 4 + 3] = v.w;
  }
  __syncthreads();

  int d     = tid >> 2;
  int cpart = (tid & 3) * 16;
  short* dst = Wt + ((size_t)(proj * H_NUM + h) * D_HEAD + d) * C_DIM + cb * 64 + cpart;
  short8 o0, o1;
#pragma unroll
  for (int j = 0; j < 8; j++) {
    o0[j] = f2bf(tile[cpart + j][d]);
    o1[j] = f2bf(tile[cpart + 8 + j][d]);
  }
  *reinterpret_cast<short8*>(dst)     = o0;
  *reinterpret_cast<short8*>(dst + 8) = o1;
}

// ---------------------------------------------------------------------------
// GEMM: C[M,N] = A[M,K] @ Bt[N,K]^T, bf16 in, f32 accum. (r19 structure —
// best measured: BMTx128 tile, BK=32, linear LDS + chunk-XOR fragment swizzle,
// global_load_lds w=16, 3-deep staging + counted vmcnt, XCD-chunked swizzle,
// no setprio. MODE 0: LDS-coalesced scatter epilogue. MODE 1: bias + f32.
// ---------------------------------------------------------------------------
template <int MODE, int BMT>
__global__ __launch_bounds__(256) void gemm_bt(
    const short* __restrict__ A, const short* __restrict__ Bt,
    const float* __restrict__ bias,
    short* __restrict__ qb, short* __restrict__ kb, short* __restrict__ vtb,
    float* __restrict__ outb,
    int M, int N, int K) {
  constexpr int BK = 32;
  constexpr int MR = BMT / 32;
  constexpr int NLA = BMT / 64;
  __shared__ short GL[3 * (BMT + 128) * BK];
  short* Asb = GL;
  short* Bsb = GL + 3 * BMT * BK;

  int tid  = threadIdx.x;
  int lane = tid & 63;
  int wv   = tid >> 6;
  int q15  = lane & 15, g = lane >> 4;
  int ntn  = N >> 7;
  int bpx  = (M / BMT) >> 3;
  int xcd  = blockIdx.x & 7;
  int idx  = blockIdx.x >> 3;
  int bn   = idx / bpx;
  int bm   = xcd * bpx + (idx - bn * bpx);
  int row0 = bm * BMT, col0 = bn << 7;
  int wm   = (wv >> 1) * (BMT / 2);
  int wn   = (wv & 1) << 6;

  f32x4 acc[MR][4];
#pragma unroll
  for (int i = 0; i < MR; i++)
#pragma unroll
    for (int j = 0; j < 4; j++) acc[i][j] = (f32x4){0.f, 0.f, 0.f, 0.f};

  int srccol = ((tid & 3) ^ ((tid >> 3) & 3)) * 8;
  const short* ag = A  + (size_t)(row0 + (tid >> 2)) * K + srccol;
  const short* bg = Bt + (size_t)(col0 + (tid >> 2)) * K + srccol;
  const size_t gstep = (size_t)64 * K;

  auto stage = [&](int ks, int buf) {
    const short* a  = ag + (size_t)ks * BK;
    const short* bb = bg + (size_t)ks * BK;
    gld_lds16(Asb + buf * BMT * BK + tid * 8, a);
    if constexpr (NLA == 2)
      gld_lds16(Asb + buf * BMT * BK + 64 * BK + tid * 8, a + gstep);
    gld_lds16(Bsb + buf * 128 * BK + tid * 8, bb);
    gld_lds16(Bsb + buf * 128 * BK + 64 * BK + tid * 8, bb + gstep);
  };

  int nk = K / BK;
  stage(0, 0);
  stage(1, 1);
  if constexpr (NLA == 2) {
    asm volatile("s_waitcnt vmcnt(4)" ::: "memory");
  } else {
    asm volatile("s_waitcnt vmcnt(3)" ::: "memory");
  }
  __builtin_amdgcn_s_barrier();
  __builtin_amdgcn_sched_barrier(0);

  int rpos = (g ^ ((q15 >> 1) & 3)) * 8;

  for (int k = 0; k < nk; ++k) {
    int buf = k % 3;
    if (k + 2 < nk) stage(k + 2, (k + 2) % 3);

    short8 af[MR], bf[4];
#pragma unroll
    for (int mi = 0; mi < MR; mi++)
      af[mi] = *reinterpret_cast<const short8*>(
          &Asb[buf * BMT * BK + (wm + mi * 16 + q15) * BK + rpos]);
#pragma unroll
    for (int ni = 0; ni < 4; ni++)
      bf[ni] = *reinterpret_cast<const short8*>(
          &Bsb[buf * 128 * BK + (wn + ni * 16 + q15) * BK + rpos]);
#pragma unroll
    for (int mi = 0; mi < MR; mi++)
#pragma unroll
      for (int ni = 0; ni < 4; ni++)
        acc[mi][ni] = __builtin_amdgcn_mfma_f32_16x16x32_bf16(af[mi], bf[ni],
                                                              acc[mi][ni], 0, 0, 0);

    if (k + 1 < nk) {
      if (k + 2 < nk) {
        if constexpr (NLA == 2) { BAR_VM(4); } else { BAR_VM(3); }
      } else {
        BAR_VM(0);
      }
    }
  }

  // ---------------- epilogue ----------------
  if constexpr (MODE == 0) {
    constexpr int LDT = 136;
    int proj  = col0 >> 10;
    int b     = row0 >> 11;
    int trow0 = row0 & (T_SEQ - 1);
    int h0    = (col0 >> 6) & 15;
    __syncthreads();
    if (proj < 2) {
      float scl = (proj == 0) ? 0.125f * 1.44269504f : 1.0f;  // log2-domain q
#pragma unroll
      for (int mi = 0; mi < MR; mi++)
#pragma unroll
        for (int ni = 0; ni < 4; ni++) {
          int t0 = wm + mi * 16 + (g << 2);
          int d2 = wn + ni * 16 + q15;
#pragma unroll
          for (int r = 0; r < 4; r++)
            GL[(t0 + r) * LDT + d2] = f2bf(acc[mi][ni][r] * scl);
        }
      __syncthreads();
      short* dstb = (proj == 0) ? qb : kb;
#pragma unroll
      for (int ps = 0; ps < 8; ps++) {
        int trow  = ps * 16 + (tid >> 4);
        int chunk = tid & 15;
        int hh    = h0 + (chunk >> 3);
        int d     = (chunk & 7) * 8;
        short8 v = *reinterpret_cast<const short8*>(&GL[trow * LDT + chunk * 8]);
        *reinterpret_cast<short8*>(
            dstb + ((size_t)(b * H_NUM + hh) * T_SEQ + trow0 + trow) * D_HEAD + d) = v;
      }
    } else {
#pragma unroll
      for (int mi = 0; mi < MR; mi++)
#pragma unroll
        for (int ni = 0; ni < 4; ni++) {
          int t0 = wm + mi * 16 + (g << 2);
          int d2 = wn + ni * 16 + q15;
          short4v pk;
#pragma unroll
          for (int r = 0; r < 4; r++) pk[r] = f2bf(acc[mi][ni][r]);
          *reinterpret_cast<short4v*>(&GL[d2 * LDT + t0]) = pk;
        }
      __syncthreads();
#pragma unroll
      for (int ps = 0; ps < 8; ps++) {
        int drow  = ps * 16 + (tid >> 4);
        int chunk = tid & 15;
        int hh    = h0 + (drow >> 6);
        int d     = drow & 63;
        short8 v = *reinterpret_cast<const short8*>(&GL[drow * LDT + chunk * 8]);
        *reinterpret_cast<short8*>(
            vtb + ((size_t)(b * H_NUM + hh) * D_HEAD + d) * T_SEQ + trow0 +
            chunk * 8) = v;
      }
    }
  } else {
#pragma unroll
    for (int mi = 0; mi < MR; mi++) {
#pragma unroll
      for (int ni = 0; ni < 4; ni++) {
        int rb  = row0 + wm + mi * 16 + (g << 2);
        int col = col0 + wn + ni * 16 + q15;
        f32x4 v = acc[mi][ni];
        float bb = bias[col];
#pragma unroll
        for (int r = 0; r < 4; r++)
          outb[(size_t)(rb + r) * N + col] = v[r] + bb;
      }
    }
  }
}

// ---------------------------------------------------------------------------
// Flash attention (r19 version — best measured, 43.6-43.8 us): swapped S^T,
// LDS 2-buf K/V (coalesced staging), 1024 blocks = 4 blocks/CU, quartile-
// alternating strips, 4 heads/XCD, log2-domain softmax, ones-MFMA row-sum,
// v_perm bf16 pack, no setprio (lockstep).
// ---------------------------------------------------------------------------
__global__ __launch_bounds__(256, 4) void attn_fwd(const short* __restrict__ qg,
                                                   const short* __restrict__ kg,
                                                   const short* __restrict__ vt,
                                                   short* __restrict__ ob) {
  int bid  = blockIdx.x;
  int q2   = bid >> 8;                  // 0..3 (quartile)
  int r    = bid & 255;
  int bh   = (r & 7) * 4 + q2;          // XCD (bid&7) sees 4 heads
  int sb   = r >> 3;                    // 0..31
  int strip = (q2 & 1) ? sb : 31 - sb;  // quartile-alternating: CU sum const
  int b    = bh >> 4;
  int h    = bh & 15;
  int tid  = threadIdx.x, lane = tid & 63, wv = tid >> 6;
  int q15  = lane & 15, g = lane >> 4;
  int qr   = strip * 64 + wv * 16;      // wave's 16 q rows

  __shared__ short arena[16384];

  const short* qp = qg + (size_t)bh * T_SEQ * D_HEAD;
  const short* kp = kg + (size_t)bh * T_SEQ * D_HEAD;
  const short* vp = vt + (size_t)bh * D_HEAD * T_SEQ;

  int r8    = lane >> 3;
  int gcb   = ((lane & 7) * 16) ^ (r8 << 4);
  int srow0 = wv * 16;

  int hh = (q15 & 7) << 4;
  int koff0 = ((0 * 64 + g * 16) ^ hh) >> 1;
  int koff1 = ((1 * 64 + g * 16) ^ hh) >> 1;
  int voff[4];
#pragma unroll
  for (int st = 0; st < 4; st++) voff[st] = ((st * 32 + g * 8) ^ hh) >> 1;

  short8 qf[2];
#pragma unroll
  for (int kk = 0; kk < 2; kk++)
    qf[kk] = *reinterpret_cast<const short8*>(
        qp + (size_t)(qr + q15) * D_HEAD + kk * 32 + g * 8);

  f32x4 acc[4];
#pragma unroll
  for (int dt = 0; dt < 4; dt++) acc[dt] = (f32x4){0.f, 0.f, 0.f, 0.f};
  f32x4 lacc = (f32x4){0.f, 0.f, 0.f, 0.f};
  float m_ = -1e30f;

  const short4v ones4 = (short4v){(short)0x3F80, (short)0x3F80,
                                  (short)0x3F80, (short)0x3F80};

  int nch = strip + 1;

  auto stage = [&](int c, int pbuf) {
    const short* ks = kp + (size_t)(c * 64 + srow0 + r8) * D_HEAD + (gcb >> 1);
    const short* vs = vp + (size_t)(srow0 + r8) * T_SEQ + c * 64 + (gcb >> 1);
    short* kd = arena + pbuf * 4096 + srow0 * 64 + lane * 8;
    short* vd = arena + 8192 + pbuf * 4096 + srow0 * 64 + lane * 8;
    gld_lds16(kd, ks);
    gld_lds16(kd + 8 * 64, ks + (size_t)8 * D_HEAD);
    gld_lds16(vd, vs);
    gld_lds16(vd + 8 * 64, vs + (size_t)8 * T_SEQ);
  };

  stage(0, 0);
  BAR_VM(0);

  for (int c = 0; c < nch; ++c) {
    int s0 = c * 64;
    if (c + 1 < nch) stage(c + 1, (c + 1) & 1);
    const short* Kb = arena + (c & 1) * 4096;
    const short* Vb = arena + 8192 + (c & 1) * 4096;

    short8 kf[4][2];
#pragma unroll
    for (int st = 0; st < 4; st++) {
      int rbase = (st * 16 + q15) * 64;
      kf[st][0] = *reinterpret_cast<const short8*>(&Kb[rbase + koff0]);
      kf[st][1] = *reinterpret_cast<const short8*>(&Kb[rbase + koff1]);
    }

    f32x4 sv[4];
#pragma unroll
    for (int st = 0; st < 4; st++) {
      f32x4 s = (f32x4){0.f, 0.f, 0.f, 0.f};
      s = __builtin_amdgcn_mfma_f32_16x16x32_bf16(kf[st][0], qf[0], s, 0, 0, 0);
      s = __builtin_amdgcn_mfma_f32_16x16x32_bf16(kf[st][1], qf[1], s, 0, 0, 0);
      sv[st] = s;
    }

    short4v vf[4][4];
#pragma unroll
    for (int st = 0; st < 4; st++)
#pragma unroll
      for (int dt = 0; dt < 4; dt++)
        vf[st][dt] = *reinterpret_cast<const short4v*>(
            &Vb[(dt * 16 + q15) * 64 + voff[st]]);

    if (c == nch - 1) {
#pragma unroll
      for (int st = 0; st < 4; st++)
#pragma unroll
        for (int r2 = 0; r2 < 4; r2++) {
          int sg = s0 + st * 16 + g * 4 + r2;
          if (sg > qr + q15) sv[st][r2] = -1e30f;
        }
    }

    float t0 = fmaxf(fmaxf(sv[0][0], sv[0][1]), sv[0][2]);
    float t1 = fmaxf(fmaxf(sv[0][3], sv[1][0]), sv[1][1]);
    float t2 = fmaxf(fmaxf(sv[1][2], sv[1][3]), sv[2][0]);
    float t3 = fmaxf(fmaxf(sv[2][1], sv[2][2]), sv[2][3]);
    float t4 = fmaxf(fmaxf(sv[3][0], sv[3][1]), sv[3][2]);
    float mx = fmaxf(fmaxf(fmaxf(t0, t1), t2),
                     fmaxf(fmaxf(t3, t4), sv[3][3]));
    mx = fmaxf(mx, __shfl_xor(mx, 16));
    mx = fmaxf(mx, __shfl_xor(mx, 32));

    if (!__all(mx <= m_ + 11.5f)) {
      float mnew = fmaxf(m_, mx);
      float sc   = __builtin_amdgcn_exp2f(m_ - mnew);
      m_ = mnew;
      lacc *= sc;
#pragma unroll
      for (int dt = 0; dt < 4; dt++) acc[dt] *= sc;
    }
    float mcur = m_;

    short4v pbf[4];
#pragma unroll
    for (int st = 0; st < 4; st++) {
      float p0 = __builtin_amdgcn_exp2f(sv[st][0] - mcur);
      float p1 = __builtin_amdgcn_exp2f(sv[st][1] - mcur);
      float p2 = __builtin_amdgcn_exp2f(sv[st][2] - mcur);
      float p3 = __builtin_amdgcn_exp2f(sv[st][3] - mcur);
      union { short4v s; unsigned u[2]; } P;
      P.u[0] = pk2bf(p0, p1);
      P.u[1] = pk2bf(p2, p3);
      pbf[st] = P.s;
    }

#pragma unroll
    for (int st = 0; st < 4; st++) {
#if __has_builtin(__builtin_amdgcn_mfma_f32_16x16x16bf16_1k)
      lacc = __builtin_amdgcn_mfma_f32_16x16x16bf16_1k(ones4, pbf[st], lacc, 0, 0, 0);
#pragma unroll
      for (int dt = 0; dt < 4; dt++)
        acc[dt] = __builtin_amdgcn_mfma_f32_16x16x16bf16_1k(
            vf[st][dt], pbf[st], acc[dt], 0, 0, 0);
#else
      short4v p4 = pbf[st];
      short8 bz = (short8){p4[0], p4[1], p4[2], p4[3], 0, 0, 0, 0};
      short8 oz = (short8){(short)0x3F80, (short)0x3F80, (short)0x3F80,
                           (short)0x3F80, 0, 0, 0, 0};
      lacc = __builtin_amdgcn_mfma_f32_16x16x32_bf16(oz, bz, lacc, 0, 0, 0);
#pragma unroll
      for (int dt = 0; dt < 4; dt++) {
        short4v v4 = vf[st][dt];
        short8 az = (short8){v4[0], v4[1], v4[2], v4[3], 0, 0, 0, 0};
        acc[dt] =
            __builtin_amdgcn_mfma_f32_16x16x32_bf16(az, bz, acc[dt], 0, 0, 0);
      }
#endif
    }

    BAR_VM(0);
  }

  short* OlW = arena + wv * (16 * 68);
  float inv = 1.0f / lacc[0];
#pragma unroll
  for (int dt = 0; dt < 4; dt++)
#pragma unroll
    for (int r2 = 0; r2 < 4; r2++)
      OlW[q15 * 68 + dt * 16 + g * 4 + r2] = f2bf(acc[dt][r2] * inv);
  int row = lane >> 2, cb = (lane & 3) * 16;
  size_t base = ((size_t)(b * T_SEQ) + qr + row) * C_DIM + h * 64 + cb;
  const short* src = OlW + row * 68 + cb;
  *reinterpret_cast<short8*>(ob + base) = *reinterpret_cast<const short8*>(src);
  *reinterpret_cast<short8*>(ob + base + 8) =
      *reinterpret_cast<const short8*>(src + 8);
}

// ---------------------------------------------------------------------------
// Launch. Workspace layout (needs >= 40 MB):
//   [0, 8M)        xb   bf16 x cast            (reused as obuf after QKV GEMM)
//   [8M, 14.3M)    Wt   bf16 packed QKV weights [3072][1024]
//   [14M, 16M)     Wob  bf16 Wo [1024][1024]
//   [16M, 24M)     qb   bf16 [B,H,T,D]  (prescaled by 0.125*log2e)
//   [24M, 32M)     kb   bf16 [B,H,T,D]
//   [32M, 40M)     vtb  bf16 [B,H,D,T]
// ---------------------------------------------------------------------------
extern "C" void kernel_launch(void* const* d_in, const int* in_sizes, int n_in,
                              void* d_out, int out_size, void* d_ws, size_t ws_size,
                              hipStream_t stream) {
  const float* x  = (const float*)d_in[0];
  const float* Wq = (const float*)d_in[1];
  const float* Wk = (const float*)d_in[2];
  const float* Wv = (const float*)d_in[3];
  const float* Wo = (const float*)d_in[4];
  const float* bo = (const float*)d_in[5];
  float* out = (float*)d_out;

  char* ws = (char*)d_ws;
  short* xb   = (short*)(ws + 0);
  short* Wt   = (short*)(ws + 8388608);
  short* Wob  = (short*)(ws + 14680064);
  short* qb   = (short*)(ws + 16777216);
  short* kb   = (short*)(ws + 25165824);
  short* vtb  = (short*)(ws + 33554432);
  short* obuf = xb;  // reuse after QKV GEMM consumed xb

  prep<<<3328, 256, 0, stream>>>(x, Wo, Wq, Wk, Wv, xb, Wob, Wt);

  gemm_bt<0, 128><<<(M_ROWS / 128) * (N_QKV / 128), 256, 0, stream>>>(
      xb, Wt, nullptr, qb, kb, vtb, nullptr, M_ROWS, N_QKV, C_DIM);

  attn_fwd<<<1024, 256, 0, stream>>>(qb, kb, vtb, obuf);

  gemm_bt<1, 64><<<(M_ROWS / 64) * (C_DIM / 128), 256, 0, stream>>>(
      obuf, Wob, bo, nullptr, nullptr, nullptr, out, M_ROWS, C_DIM, C_DIM);
}